// Round 9
// baseline (162.577 us; speedup 1.0000x reference)
//
#include <hip/hip_runtime.h>
#include <stdint.h>

// LinearAttention: x[2,8192,1024] -> qkv proj -> per-head softmaxes ->
// context = softmax_n(k)^T v -> out = softmax_d(q) @ ctx -> @ W_out + b.
//
// R9: ctx_partial rewritten as 8x8 per-lane outer product (old version was
// LDS-read-port-bound: 4096 b128/CU ~ 20us; new: 4x fewer reads, FMA:read
// 32:1). ctx_reduce merged into ctxw. GEMM structure = R7/R8-measured
// (128x128, BK=64, 4 waves, 64KB LDS, 2 blocks/CU; fused softmax(q)/exp(k)
// epilogue; out = softq @ (ctx@W_out) with per-batch CW^T).

typedef _Float16 half4 __attribute__((ext_vector_type(4)));
typedef _Float16 half8 __attribute__((ext_vector_type(8)));
typedef float f32x4 __attribute__((ext_vector_type(4)));

// ---- workspace byte offsets ----
#define WS_XB 0UL             // x as f16          [16384][1024]   33.55MB
#define WS_WQKVT 33554432UL   // W_qkv^T f16       [1536][1024]     3.15MB
#define WS_CWT 37748736UL     // CW^T f16          [2][1024][512]   2.10MB
#define WS_EKH 54525952UL     // exp(k) f16        [16][8192][64]  16.78MB
#define WS_VH 71303168UL      // v f16             [16][8192][64]  16.78MB
#define WS_SQ 88080384UL      // softmax(q) f16    [16384][512]    16.78MB
#define WS_CTXPART 104857600UL// ctx partials f32  [512][4096]      8.39MB
#define WS_COLPART 113246208UL// colsum partials   [512][64]        0.13MB

__device__ __forceinline__ void gld16(const void* g, void* l) {
  // async global->LDS, 16B per lane; LDS dest = wave-uniform base + lane*16
  __builtin_amdgcn_global_load_lds(
      (const __attribute__((address_space(1))) unsigned int*)g,
      (__attribute__((address_space(3))) unsigned int*)l, 16, 0, 0);
}

// Fused prep: cvt x (f32->f16), transpose+cvt W_qkv.
__global__ void prep_kernel(const float* __restrict__ x,
                            const float* __restrict__ Wqkv,
                            _Float16* __restrict__ xb,
                            _Float16* __restrict__ wqkvT) {
  const int blk = blockIdx.x;
  if (blk < 16384) {
    int i = blk * 256 + threadIdx.x;  // 4 f32 per thread
    f32x4 v = *(const f32x4*)(x + (size_t)i * 4);
    half4 h = {(_Float16)v[0], (_Float16)v[1], (_Float16)v[2], (_Float16)v[3]};
    *(half4*)(xb + (size_t)i * 4) = h;
  } else {
    int i = (blk - 16384) * 256 + threadIdx.x;  // [0, 1536*1024)
    int c = i >> 10, r = i & 1023;
    wqkvT[i] = (_Float16)Wqkv[(size_t)r * 1536 + c];
  }
}

// ---------------- 128x128 BK=64 co-resident GEMM (R7-measured) -------------
// A[M][K] f16 row-major, BT[N][K] f16 row-major. 256 threads = 4 waves (2Mx2N),
// per-wave output 64x64 (acc[4][4]). LDS: 2 dbuf x (A 16KB + B 16KB) = 64KB.
// Tile layout [128 rows][128B], XOR swizzle byte ^= ((row&7)<<4); staged
// linearly via global_load_lds with inverse-swizzled global source column.

// stage one full 128x64-f16 tile region = 4 sweeps x 1 gld16/thread
__device__ __forceinline__ void stage_tile(const _Float16* __restrict__ G, int K,
                                           int rowbase, int kt, char* region,
                                           int t) {
  char* wbase = region + (t & ~63) * 16;  // + lane*16 done by HW
#pragma unroll
  for (int q = 0; q < 4; ++q) {
    const int row = q * 32 + (t >> 3);
    const int col8 = ((t & 7) ^ (row & 7)) * 8;  // inverse-swizzled f16 col
    gld16(G + (size_t)(rowbase + row) * K + kt + col8, wbase + q * 4096);
  }
}

// EPI 0: softmax(q)->oQ[16384][512]; exp(k)->oK per-head; v->oV per-head.
// EPI 1: +bias, f32 out ldc=1024 (A=softq, BT=CW^T per batch via bstride).
template <int EPI>
__global__ __launch_bounds__(256, 2) void gemm128(
    const _Float16* __restrict__ A, const _Float16* __restrict__ BT, int K,
    int NTN, int bstride, _Float16* __restrict__ oQ, _Float16* __restrict__ oK,
    _Float16* __restrict__ oV, float* __restrict__ oC,
    const float* __restrict__ bias) {
  __shared__ char lds[65536];
  const int t = threadIdx.x;
  const int l = t & 63, w = t >> 6;
  const int wm = w >> 1, wn = w & 1;  // wave -> 64x64 quadrant
  const int fr = l & 15, qq = l >> 4;
  const int swzx = (fr & 7) << 4;

  // T1: bijective XCD chunking (nwg % 8 == 0), tileM-major within chunk
  const int nwg = gridDim.x;
  const int cpx = nwg >> 3;
  const int wg = (blockIdx.x & 7) * cpx + (blockIdx.x >> 3);
  const int tileM = wg / NTN, tileN = wg - tileM * NTN;
  const int mbase = tileM * 128, nbase = tileN * 128;
  BT += (size_t)(tileM >> 6) * bstride;  // per-batch B (0 for GEMM1)

  const int NT = K >> 6;
  f32x4 acc[4][4] = {};
  half8 a[4][2], b[4][2];

  // stage both operands of K-tile `tile` into buffer (tile&1)
  auto STG = [&](int tile) {
    int kt = tile * 64;
    if (kt > K - 64) kt = K - 64;  // tail clamp: identical issue counts
    char* base = lds + ((tile & 1) << 15);
    stage_tile(A, K, mbase, kt, base, t);          // 4 loads
    stage_tile(BT, K, nbase, kt, base + 16384, t); // 4 loads
  };

  // prologue: tile0 + tile1 (16 loads/thread); vmcnt(8) -> tile0 resident
  STG(0);
  STG(1);
  asm volatile("s_waitcnt vmcnt(8)" ::: "memory");
  __builtin_amdgcn_s_barrier();

  for (int t2 = 0; t2 < NT; ++t2) {
    const char* ldsA = lds + ((t2 & 1) << 15);
    const char* ldsB = ldsA + 16384;
    // ph0: stage tile t2+1 -> other buffer (prev readers drained at ph1's
    // lgkmcnt(0) before BAR_b); then all frag reads from cur.
    STG(t2 + 1);
#pragma unroll
    for (int mi = 0; mi < 4; ++mi)
#pragma unroll
      for (int kk = 0; kk < 2; ++kk) {
        int off = (wm * 64 + mi * 16 + fr) * 128 + ((kk * 64 + qq * 16) ^ swzx);
        a[mi][kk] = *(const half8*)(ldsA + off);
      }
#pragma unroll
    for (int ni = 0; ni < 4; ++ni)
#pragma unroll
      for (int kk = 0; kk < 2; ++kk) {
        int off = (wn * 64 + ni * 16 + fr) * 128 + ((kk * 64 + qq * 16) ^ swzx);
        b[ni][kk] = *(const half8*)(ldsB + off);
      }
    __builtin_amdgcn_s_barrier();  // BAR_a
    __builtin_amdgcn_s_setprio(1);
#pragma unroll
    for (int mi = 0; mi < 4; ++mi)
#pragma unroll
      for (int ni = 0; ni < 2; ++ni)
#pragma unroll
        for (int kk = 0; kk < 2; ++kk)
          acc[mi][ni] = __builtin_amdgcn_mfma_f32_16x16x32_f16(
              a[mi][kk], b[ni][kk], acc[mi][ni], 0, 0, 0);
    __builtin_amdgcn_s_setprio(0);
    // ph1: drain this tile's ds_reads so next iter's STG->other is race-free;
    // drain stage loads (t2+1).
    asm volatile("s_waitcnt vmcnt(0) lgkmcnt(0)" ::: "memory");
    __builtin_amdgcn_s_barrier();  // BAR_b
    __builtin_amdgcn_s_setprio(1);
#pragma unroll
    for (int mi = 0; mi < 4; ++mi)
#pragma unroll
      for (int ni = 2; ni < 4; ++ni)
#pragma unroll
        for (int kk = 0; kk < 2; ++kk)
          acc[mi][ni] = __builtin_amdgcn_mfma_f32_16x16x32_f16(
              a[mi][kk], b[ni][kk], acc[mi][ni], 0, 0, 0);
    __builtin_amdgcn_s_setprio(0);
  }

  // C/D layout: col = lane&15 (=fr), row = (lane>>4)*4 + reg (=qq*4+r)
  if (EPI == 0) {
    // wave's 64-col range is 64-aligned -> single `which`, single head
    const int gcol0 = nbase + wn * 64;
    const int which = gcol0 >> 9;
    if (which == 0) {
      // fused softmax over head dim (4 in-reg + shfl_xor<16), store softq
#pragma unroll
      for (int mi = 0; mi < 4; ++mi) {
        const int grow = mbase + wm * 64 + mi * 16 + qq * 4;
        float e[4][4], rs[4];
#pragma unroll
        for (int r = 0; r < 4; ++r) {
          float s = 0.f;
#pragma unroll
          for (int ni = 0; ni < 4; ++ni) {
            e[ni][r] = __expf(acc[mi][ni][r]);
            s += e[ni][r];
          }
#pragma unroll
          for (int off = 1; off < 16; off <<= 1) s += __shfl_xor(s, off, 64);
          rs[r] = 1.f / s;
        }
#pragma unroll
        for (int ni = 0; ni < 4; ++ni) {
          const int gcol = gcol0 + ni * 16 + fr;
#pragma unroll
          for (int r = 0; r < 4; ++r)
            oQ[(size_t)(grow + r) * 512 + gcol] = (_Float16)(e[ni][r] * rs[r]);
        }
      }
    } else {
      // k: store exp(logit) f16 (range <= e^~6, f16-safe); v: plain f16
      _Float16* dst0 = (which == 1) ? oK : oV;
      const int h = (gcol0 >> 6) & 7;
#pragma unroll
      for (int mi = 0; mi < 4; ++mi) {
        const int grow = mbase + wm * 64 + mi * 16 + qq * 4;
        const int bidx = grow >> 13, n = grow & 8191;
        const size_t rb = ((size_t)((bidx << 3) + h) * 8192 + n) * 64;
#pragma unroll
        for (int ni = 0; ni < 4; ++ni) {
          const int d = ni * 16 + fr;
#pragma unroll
          for (int r = 0; r < 4; ++r) {
            float v = acc[mi][ni][r];
            if (which == 1) v = __expf(v);
            dst0[rb + (size_t)r * 64 + d] = (_Float16)v;
          }
        }
      }
    }
  } else {
#pragma unroll
    for (int mi = 0; mi < 4; ++mi) {
      const int grow = mbase + wm * 64 + mi * 16 + qq * 4;
#pragma unroll
      for (int ni = 0; ni < 4; ++ni) {
        const int gcol = nbase + wn * 64 + ni * 16 + fr;
        const float bb = bias[gcol];
#pragma unroll
        for (int r = 0; r < 4; ++r)
          oC[(size_t)(grow + r) * 1024 + gcol] = acc[mi][ni][r] + bb;
      }
    }
  }
}

// ctx partials: block = (bh, 256-n chunk); 4 waves, wave w owns n-range
// [w*64, +64). Stage raw f16 ek/v (exp already applied upstream) via async
// gld16 (64KB). Lane computes 8x8 f32 outer product (d0=(l&7)*8,
// e0=(l>>3)*8); all lanes read the same LDS row -> broadcast, conflict-free.
// Then smem is reused as 4x 64x64 f32 reduce buffer. Deterministic.
__global__ __launch_bounds__(256, 2) void ctx_partial_kernel(
    const _Float16* __restrict__ ekh, const _Float16* __restrict__ vh,
    float* __restrict__ ctxpart, float* __restrict__ colpart) {
  __shared__ char smem[65536];
  __shared__ float credu[4][64];
  _Float16* sek = (_Float16*)smem;            // [256][64] f16, 32KB
  _Float16* svv = (_Float16*)(smem + 32768);  // [256][64] f16, 32KB
  const int t = threadIdx.x, l = t & 63, w = t >> 6;
  const int bh = blockIdx.x >> 5, ch = blockIdx.x & 31;
  const size_t rowbase = ((size_t)bh * 8192 + ch * 256) * 64;
  {
    const char* eksrc = (const char*)(ekh + rowbase);
    const char* vsrc = (const char*)(vh + rowbase);
    char* ekbase = smem + w * 1024;
    char* vbase = smem + 32768 + w * 1024;
#pragma unroll
    for (int s = 0; s < 8; ++s) {
      gld16(eksrc + (size_t)(s * 256 + t) * 16, ekbase + s * 4096);
      gld16(vsrc + (size_t)(s * 256 + t) * 16, vbase + s * 4096);
    }
  }
  asm volatile("s_waitcnt vmcnt(0)" ::: "memory");
  __builtin_amdgcn_s_barrier();

  const int d0 = (l & 7) * 8, e0 = (l >> 3) * 8;
  f32x4 acc[8][2] = {};
  float cacc[8] = {};
  const int n0 = w * 64;
  for (int n = n0; n < n0 + 64; ++n) {
    half8 k8 = *(const half8*)&sek[n * 64 + d0];
    half8 v8 = *(const half8*)&svv[n * 64 + e0];
    float e[8];
    f32x4 v4[2];
#pragma unroll
    for (int i = 0; i < 8; ++i) e[i] = (float)k8[i];
#pragma unroll
    for (int j = 0; j < 8; ++j) v4[j >> 2][j & 3] = (float)v8[j];
#pragma unroll
    for (int i = 0; i < 8; ++i) {
      cacc[i] += e[i];
      acc[i][0] += v4[0] * e[i];
      acc[i][1] += v4[1] * e[i];
    }
  }
  __builtin_amdgcn_s_barrier();  // all waves done reading sek/svv
  float* red = (float*)smem;     // reuse: [4][64][64] f32 = 64KB
#pragma unroll
  for (int i = 0; i < 8; ++i) {
    *(f32x4*)&red[w * 4096 + (d0 + i) * 64 + e0] = acc[i][0];
    *(f32x4*)&red[w * 4096 + (d0 + i) * 64 + e0 + 4] = acc[i][1];
  }
  if (l < 8) {
#pragma unroll
    for (int i = 0; i < 8; ++i) credu[w][l * 8 + i] = cacc[i];
  }
  __syncthreads();
  float* cp = ctxpart + (size_t)blockIdx.x * 4096;
#pragma unroll
  for (int s = 0; s < 4; ++s) {
    const int r = t * 16 + s * 4;
    f32x4 sum = *(const f32x4*)&red[r];
    sum += *(const f32x4*)&red[4096 + r];
    sum += *(const f32x4*)&red[8192 + r];
    sum += *(const f32x4*)&red[12288 + r];
    *(f32x4*)&cp[r] = sum;
  }
  if (t < 64)
    colpart[blockIdx.x * 64 + t] =
        credu[0][t] + credu[1][t] + credu[2][t] + credu[3][t];
}

// Merged reduce + CW^T: block = (bh, d). Reduces ctxpart/colpart for this
// (bh,d) row, divides, then CW^T[b][o][h*64+d] = sum_e crow[e]*Wout[h*64+e][o].
__global__ __launch_bounds__(256) void ctxw_kernel(
    const float* __restrict__ ctxpart, const float* __restrict__ colpart,
    const float* __restrict__ Wout, _Float16* __restrict__ cwT) {
  __shared__ float part[4][64];
  __shared__ float csp[32];
  __shared__ float crow[64];
  const int blk = blockIdx.x;
  const int bh = blk >> 6, d = blk & 63;
  const int b = bh >> 3, h = bh & 7;
  const int t = threadIdx.x;
  const int e = t & 63, cq = t >> 6;
  float p = 0.f;
#pragma unroll
  for (int cc = 0; cc < 8; ++cc)
    p += ctxpart[(size_t)(bh * 32 + cq * 8 + cc) * 4096 + d * 64 + e];
  part[cq][e] = p;
  if (t >= 64 && t < 96)
    csp[t - 64] = colpart[(size_t)(bh * 32 + (t - 64)) * 64 + d];
  __syncthreads();
  if (t < 64) {
    float csum = 0.f;
#pragma unroll
    for (int c = 0; c < 32; ++c) csum += csp[c];
    crow[t] = (part[0][t] + part[1][t] + part[2][t] + part[3][t]) / csum;
  }
  __syncthreads();
  float acc[4] = {};
  for (int e2 = 0; e2 < 64; ++e2) {
    const float c = crow[e2];
    const float* wr = Wout + (size_t)(h * 64 + e2) * 1024 + t;
#pragma unroll
    for (int j = 0; j < 4; ++j) acc[j] += c * wr[j * 256];
  }
  _Float16* dst = cwT + (size_t)b * 524288 + (size_t)t * 512 + h * 64 + d;
#pragma unroll
  for (int j = 0; j < 4; ++j) dst[(size_t)j * 256 * 512] = (_Float16)acc[j];
}

extern "C" void kernel_launch(void* const* d_in, const int* in_sizes, int n_in,
                              void* d_out, int out_size, void* d_ws, size_t ws_size,
                              hipStream_t stream) {
  const float* x = (const float*)d_in[0];
  const float* Wqkv = (const float*)d_in[1];
  const float* Wout = (const float*)d_in[2];
  const float* bout = (const float*)d_in[3];
  float* out = (float*)d_out;
  char* ws = (char*)d_ws;

  _Float16* xb = (_Float16*)(ws + WS_XB);
  _Float16* wqkvT = (_Float16*)(ws + WS_WQKVT);
  _Float16* cwT = (_Float16*)(ws + WS_CWT);
  _Float16* ekh = (_Float16*)(ws + WS_EKH);
  _Float16* vh = (_Float16*)(ws + WS_VH);
  _Float16* sq = (_Float16*)(ws + WS_SQ);
  float* ctxpart = (float*)(ws + WS_CTXPART);
  float* colpart = (float*)(ws + WS_COLPART);

  // 1) fused converts (x cvt + W_qkv transpose)
  prep_kernel<<<22528, 256, 0, stream>>>(x, Wqkv, xb, wqkvT);
  // 2) qkv projection + fused softmax(q)/exp(k) epilogue
  gemm128<0><<<1536, 256, 0, stream>>>(xb, wqkvT, 1024, 12, 0, sq, ekh, vh,
                                       nullptr, nullptr);
  // 3) context partials (ek^T v + colsums), deterministic
  ctx_partial_kernel<<<512, 256, 0, stream>>>(ekh, vh, ctxpart, colpart);
  // 4) reduce + CW^T = (ctx @ W_out)^T per batch
  ctxw_kernel<<<1024, 256, 0, stream>>>(ctxpart, colpart, Wout, cwT);
  // 5) out = softq @ CW + b  (M=16384,N=1024,K=512; B selected per batch)
  gemm128<1><<<1024, 256, 0, stream>>>(sq, cwT, 512, 8, 524288, nullptr,
                                       nullptr, nullptr, out, bout);
}

// Round 10
// 151.707 us; speedup vs baseline: 1.0717x; 1.0717x over previous
//
#include <hip/hip_runtime.h>
#include <stdint.h>

// LinearAttention: x[2,8192,1024] -> qkv proj -> per-head softmaxes ->
// context = softmax_n(k)^T v -> out = softmax_d(q) @ ctx -> @ W_out + b.
//
// R10: ctx fused into GEMM1. kv blocks compute B-cols [k_h | v_h] (128 cols),
// epilogue: exp(k-quadrant) -> LDS f32 [128][128] -> 64x64 partial ek^T v +
// colsums -> ctxpart/colpart. ekh/vh tensors and ctx_partial kernel deleted
// (saves 33.5MB write + 33.5MB read + one launch). q blocks: fused softmax
// epilogue (R8-measured). GEMM structure = R7-measured 128x128/BK64/4-wave/
// 64KB-LDS, 2 blocks/CU. out = softq @ (ctx@W_out) via per-batch CW^T.

typedef _Float16 half4 __attribute__((ext_vector_type(4)));
typedef _Float16 half8 __attribute__((ext_vector_type(8)));
typedef float f32x4 __attribute__((ext_vector_type(4)));

// ---- workspace byte offsets ----
#define WS_XB 0UL             // x as f16           [16384][1024]   33.55MB
#define WS_WQKVT 33554432UL   // W_qkv^T f16        [1536][1024]     3.15MB
#define WS_CWT 37748736UL     // CW^T f16           [2][1024][512]   2.10MB
#define WS_CTXPART 54525952UL // ctx partials f32   [16][64][4096]  16.78MB
#define WS_COLPART 71303168UL // colsum partials f32[16][64][64]     0.26MB
#define WS_SQ 88080384UL      // softmax(q) f16     [16384][512]    16.78MB

__device__ __forceinline__ void gld16(const void* g, void* l) {
  // async global->LDS, 16B per lane; LDS dest = wave-uniform base + lane*16
  __builtin_amdgcn_global_load_lds(
      (const __attribute__((address_space(1))) unsigned int*)g,
      (__attribute__((address_space(3))) unsigned int*)l, 16, 0, 0);
}

// Fused prep: cvt x (f32->f16), transpose+cvt W_qkv.
__global__ void prep_kernel(const float* __restrict__ x,
                            const float* __restrict__ Wqkv,
                            _Float16* __restrict__ xb,
                            _Float16* __restrict__ wqkvT) {
  const int blk = blockIdx.x;
  if (blk < 16384) {
    int i = blk * 256 + threadIdx.x;  // 4 f32 per thread
    f32x4 v = *(const f32x4*)(x + (size_t)i * 4);
    half4 h = {(_Float16)v[0], (_Float16)v[1], (_Float16)v[2], (_Float16)v[3]};
    *(half4*)(xb + (size_t)i * 4) = h;
  } else {
    int i = (blk - 16384) * 256 + threadIdx.x;  // [0, 1536*1024)
    int c = i >> 10, r = i & 1023;
    wqkvT[i] = (_Float16)Wqkv[(size_t)r * 1536 + c];
  }
}

// ---------------- 128x128 BK=64 co-resident GEMM (R7-measured) -------------
// A[M][K] f16 row-major, BT[N][K] f16 row-major. 256 threads = 4 waves (2Mx2N),
// per-wave output 64x64 (acc[4][4]). LDS: 2 dbuf x (A 16KB + B 16KB) = 64KB.
// Tile layout [128 rows][128B], XOR swizzle byte ^= ((row&7)<<4); staged
// linearly via global_load_lds with inverse-swizzled global source column.

// stage one full 128x64-f16 tile region = 4 sweeps x 1 gld16/thread
__device__ __forceinline__ void stage_tile(const _Float16* __restrict__ G, int K,
                                           int rowbase, int kt, char* region,
                                           int t) {
  char* wbase = region + (t & ~63) * 16;  // + lane*16 done by HW
#pragma unroll
  for (int q = 0; q < 4; ++q) {
    const int row = q * 32 + (t >> 3);
    const int col8 = ((t & 7) ^ (row & 7)) * 8;  // inverse-swizzled f16 col
    gld16(G + (size_t)(rowbase + row) * K + kt + col8, wbase + q * 4096);
  }
}

// stage a 64-row tile region = 2 sweeps (for split kv B-tiles)
__device__ __forceinline__ void stage_tile64(const _Float16* __restrict__ G,
                                             int K, int rowbase, int kt,
                                             char* region, int t) {
  char* wbase = region + (t & ~63) * 16;
#pragma unroll
  for (int q = 0; q < 2; ++q) {
    const int row = q * 32 + (t >> 3);
    const int col8 = ((t & 7) ^ (row & 7)) * 8;
    gld16(G + (size_t)(rowbase + row) * K + kt + col8, wbase + q * 4096);
  }
}

// EPI 0: tileN<4 -> fused softmax(q) -> oQ[16384][512];
//        tileN>=4 -> head h=tileN-4, B-cols [k_h | v_h]; epilogue computes
//        64x64 partial ek^T v + colsums -> ctxpart/colpart.
// EPI 1: +bias, f32 out ldc=1024 (A=softq, BT=CW^T per batch via bstride).
template <int EPI>
__global__ __launch_bounds__(256, 2) void gemm128(
    const _Float16* __restrict__ A, const _Float16* __restrict__ BT, int K,
    int NTN, int bstride, _Float16* __restrict__ oQ,
    float* __restrict__ ctxpart, float* __restrict__ colpart,
    float* __restrict__ oC, const float* __restrict__ bias) {
  __shared__ char lds[65536];
  const int t = threadIdx.x;
  const int l = t & 63, w = t >> 6;
  const int wm = w >> 1, wn = w & 1;  // wave -> 64x64 quadrant
  const int fr = l & 15, qq = l >> 4;
  const int swzx = (fr & 7) << 4;

  // T1: bijective XCD chunking (nwg % 8 == 0), tileM-major within chunk
  const int nwg = gridDim.x;
  const int cpx = nwg >> 3;
  const int wg = (blockIdx.x & 7) * cpx + (blockIdx.x >> 3);
  const int tileM = wg / NTN, tileN = wg - tileM * NTN;
  const int mbase = tileM * 128, nbase = tileN * 128;
  BT += (size_t)(tileM >> 6) * bstride;  // per-batch B (0 for GEMM1)

  const int NT = K >> 6;
  f32x4 acc[4][4] = {};
  half8 a[4][2], b[4][2];

  // stage both operands of K-tile `tile` into buffer (tile&1); 8 loads/thread
  auto STG = [&](int tile) {
    int kt = tile * 64;
    if (kt > K - 64) kt = K - 64;  // tail clamp: identical issue counts
    char* base = lds + ((tile & 1) << 15);
    stage_tile(A, K, mbase, kt, base, t);  // 4 loads
    if (EPI == 1 || tileN < 4) {
      stage_tile(BT, K, nbase, kt, base + 16384, t);  // 4 loads
    } else {
      const int h = tileN - 4;
      stage_tile64(BT, K, 512 + h * 64, kt, base + 16384, t);          // k_h
      stage_tile64(BT, K, 1024 + h * 64, kt, base + 16384 + 8192, t);  // v_h
    }
  };

  // prologue: tile0 + tile1 (16 loads/thread); vmcnt(8) -> tile0 resident
  STG(0);
  STG(1);
  asm volatile("s_waitcnt vmcnt(8)" ::: "memory");
  __builtin_amdgcn_s_barrier();

  for (int t2 = 0; t2 < NT; ++t2) {
    const char* ldsA = lds + ((t2 & 1) << 15);
    const char* ldsB = ldsA + 16384;
    // ph0: stage tile t2+1 -> other buffer (prev readers drained at ph1's
    // lgkmcnt(0) before BAR_b); then all frag reads from cur.
    STG(t2 + 1);
#pragma unroll
    for (int mi = 0; mi < 4; ++mi)
#pragma unroll
      for (int kk = 0; kk < 2; ++kk) {
        int off = (wm * 64 + mi * 16 + fr) * 128 + ((kk * 64 + qq * 16) ^ swzx);
        a[mi][kk] = *(const half8*)(ldsA + off);
      }
#pragma unroll
    for (int ni = 0; ni < 4; ++ni)
#pragma unroll
      for (int kk = 0; kk < 2; ++kk) {
        int off = (wn * 64 + ni * 16 + fr) * 128 + ((kk * 64 + qq * 16) ^ swzx);
        b[ni][kk] = *(const half8*)(ldsB + off);
      }
    __builtin_amdgcn_s_barrier();  // BAR_a
    __builtin_amdgcn_s_setprio(1);
#pragma unroll
    for (int mi = 0; mi < 4; ++mi)
#pragma unroll
      for (int ni = 0; ni < 2; ++ni)
#pragma unroll
        for (int kk = 0; kk < 2; ++kk)
          acc[mi][ni] = __builtin_amdgcn_mfma_f32_16x16x32_f16(
              a[mi][kk], b[ni][kk], acc[mi][ni], 0, 0, 0);
    __builtin_amdgcn_s_setprio(0);
    // ph1: drain this tile's ds_reads so next iter's STG->other is race-free;
    // drain stage loads (t2+1).
    asm volatile("s_waitcnt vmcnt(0) lgkmcnt(0)" ::: "memory");
    __builtin_amdgcn_s_barrier();  // BAR_b
    __builtin_amdgcn_s_setprio(1);
#pragma unroll
    for (int mi = 0; mi < 4; ++mi)
#pragma unroll
      for (int ni = 2; ni < 4; ++ni)
#pragma unroll
        for (int kk = 0; kk < 2; ++kk)
          acc[mi][ni] = __builtin_amdgcn_mfma_f32_16x16x32_f16(
              a[mi][kk], b[ni][kk], acc[mi][ni], 0, 0, 0);
    __builtin_amdgcn_s_setprio(0);
  }
  // no gld16 in flight here (last stage drained at final ph1); LDS reusable.

  // C/D layout: col = lane&15 (=fr), row = (lane>>4)*4 + reg (=qq*4+r)
  if (EPI == 0) {
    if (tileN < 4) {
      // fused softmax over head dim (4 in-reg + shfl_xor<16), store softq
      const int gcol0 = nbase + wn * 64;
#pragma unroll
      for (int mi = 0; mi < 4; ++mi) {
        const int grow = mbase + wm * 64 + mi * 16 + qq * 4;
        float e[4][4], rs[4];
#pragma unroll
        for (int r = 0; r < 4; ++r) {
          float s = 0.f;
#pragma unroll
          for (int ni = 0; ni < 4; ++ni) {
            e[ni][r] = __expf(acc[mi][ni][r]);
            s += e[ni][r];
          }
#pragma unroll
          for (int off = 1; off < 16; off <<= 1) s += __shfl_xor(s, off, 64);
          rs[r] = 1.f / s;
        }
#pragma unroll
        for (int ni = 0; ni < 4; ++ni) {
          const int gcol = gcol0 + ni * 16 + fr;
#pragma unroll
          for (int r = 0; r < 4; ++r)
            oQ[(size_t)(grow + r) * 512 + gcol] = (_Float16)(e[ni][r] * rs[r]);
        }
      }
    } else {
      // kv path: local cols 0-63 = k_h logits, 64-127 = v_h.
      const int h = tileN - 4;
      float* sf = (float*)lds;  // reuse: [128 n][128 c] f32 = 64KB
#pragma unroll
      for (int mi = 0; mi < 4; ++mi) {
        const int n = wm * 64 + mi * 16 + qq * 4;
#pragma unroll
        for (int ni = 0; ni < 4; ++ni) {
          const int c = wn * 64 + ni * 16 + fr;
#pragma unroll
          for (int r = 0; r < 4; ++r) {
            float v = acc[mi][ni][r];
            if (wn == 0) v = __expf(v);  // ek = exp(k logit), f32
            sf[(size_t)(n + r) * 128 + c] = v;
          }
        }
      }
      __syncthreads();
      // 64x64 partial: thread -> (d0=(t&15)*4, e0=(t>>4)*4); LDS reads are
      // 4-way same-address broadcast (free).
      const int d0 = (t & 15) * 4, e0 = (t >> 4) * 4;
      f32x4 cacc = {0.f, 0.f, 0.f, 0.f};
      float pacc[4][4] = {};
      for (int n = 0; n < 128; ++n) {
        f32x4 ek4 = *(const f32x4*)&sf[(size_t)n * 128 + d0];
        f32x4 vv4 = *(const f32x4*)&sf[(size_t)n * 128 + 64 + e0];
        cacc += ek4;
#pragma unroll
        for (int i = 0; i < 4; ++i)
#pragma unroll
          for (int j = 0; j < 4; ++j) pacc[i][j] += ek4[i] * vv4[j];
      }
      const int bh = (tileM >> 6) * 8 + h, chunk = tileM & 63;
      float* cp = ctxpart + ((size_t)bh * 64 + chunk) * 4096;
#pragma unroll
      for (int i = 0; i < 4; ++i) {
        f32x4 o = {pacc[i][0], pacc[i][1], pacc[i][2], pacc[i][3]};
        *(f32x4*)&cp[(d0 + i) * 64 + e0] = o;
      }
      if (t < 16)  // e0==0 group holds valid per-d colsums
        *(f32x4*)&colpart[((size_t)bh * 64 + chunk) * 64 + d0] = cacc;
    }
  } else {
#pragma unroll
    for (int mi = 0; mi < 4; ++mi) {
      const int grow = mbase + wm * 64 + mi * 16 + qq * 4;
#pragma unroll
      for (int ni = 0; ni < 4; ++ni) {
        const int gcol = nbase + wn * 64 + ni * 16 + fr;
        const float bb = bias[gcol];
#pragma unroll
        for (int r = 0; r < 4; ++r)
          oC[(size_t)(grow + r) * 1024 + gcol] = acc[mi][ni][r] + bb;
      }
    }
  }
}

// Merged reduce + CW^T: block = (bh, d). Reduces 64 chunk-partials, divides
// by colsum, then CW^T[b][o][h*64+d] = sum_e crow[e]*Wout[h*64+e][o].
__global__ __launch_bounds__(256) void ctxw_kernel(
    const float* __restrict__ ctxpart, const float* __restrict__ colpart,
    const float* __restrict__ Wout, _Float16* __restrict__ cwT) {
  __shared__ float part[4][64];
  __shared__ float csp[64];
  __shared__ float crow[64];
  const int blk = blockIdx.x;
  const int bh = blk >> 6, d = blk & 63;
  const int b = bh >> 3, h = bh & 7;
  const int t = threadIdx.x;
  const int e = t & 63, cq = t >> 6;
  float p = 0.f;
#pragma unroll
  for (int cc = 0; cc < 16; ++cc)
    p += ctxpart[((size_t)bh * 64 + cq * 16 + cc) * 4096 + d * 64 + e];
  part[cq][e] = p;
  if (t >= 64 && t < 128)
    csp[t - 64] = colpart[((size_t)bh * 64 + (t - 64)) * 64 + d];
  __syncthreads();
  if (t < 64) {
    float csum = 0.f;
#pragma unroll
    for (int c = 0; c < 64; ++c) csum += csp[c];
    crow[t] = (part[0][t] + part[1][t] + part[2][t] + part[3][t]) / csum;
  }
  __syncthreads();
  float acc[4] = {};
  for (int e2 = 0; e2 < 64; ++e2) {
    const float c = crow[e2];
    const float* wr = Wout + (size_t)(h * 64 + e2) * 1024 + t;
#pragma unroll
    for (int j = 0; j < 4; ++j) acc[j] += c * wr[j * 256];
  }
  _Float16* dst = cwT + (size_t)b * 524288 + (size_t)t * 512 + h * 64 + d;
#pragma unroll
  for (int j = 0; j < 4; ++j) dst[(size_t)j * 256 * 512] = (_Float16)acc[j];
}

extern "C" void kernel_launch(void* const* d_in, const int* in_sizes, int n_in,
                              void* d_out, int out_size, void* d_ws, size_t ws_size,
                              hipStream_t stream) {
  const float* x = (const float*)d_in[0];
  const float* Wqkv = (const float*)d_in[1];
  const float* Wout = (const float*)d_in[2];
  const float* bout = (const float*)d_in[3];
  float* out = (float*)d_out;
  char* ws = (char*)d_ws;

  _Float16* xb = (_Float16*)(ws + WS_XB);
  _Float16* wqkvT = (_Float16*)(ws + WS_WQKVT);
  _Float16* cwT = (_Float16*)(ws + WS_CWT);
  _Float16* sq = (_Float16*)(ws + WS_SQ);
  float* ctxpart = (float*)(ws + WS_CTXPART);
  float* colpart = (float*)(ws + WS_COLPART);

  // 1) fused converts (x cvt + W_qkv transpose)
  prep_kernel<<<22528, 256, 0, stream>>>(x, Wqkv, xb, wqkvT);
  // 2) qkv projection; q blocks -> fused softmax -> sq; kv blocks -> fused
  //    exp(k)^T v partial-context -> ctxpart/colpart
  gemm128<0><<<1536, 256, 0, stream>>>(xb, wqkvT, 1024, 12, 0, sq, ctxpart,
                                       colpart, nullptr, nullptr);
  // 3) reduce + CW^T = (ctx @ W_out)^T per batch
  ctxw_kernel<<<1024, 256, 0, stream>>>(ctxpart, colpart, Wout, cwT);
  // 4) out = softq @ CW + b  (M=16384,N=1024,K=512; B selected per batch)
  gemm128<1><<<1024, 256, 0, stream>>>(sq, cwT, 512, 8, 524288, nullptr,
                                       nullptr, nullptr, out, bout);
}

// Round 11
// 135.899 us; speedup vs baseline: 1.1963x; 1.1163x over previous
//
#include <hip/hip_runtime.h>
#include <stdint.h>

// LinearAttention: x[2,8192,1024] -> qkv proj -> per-head softmaxes ->
// context = softmax_n(k)^T v -> out = softmax_d(q) @ ctx -> @ W_out + b.
//
// R11: kv-epilogue ctx partial now MFMA-based (R10's VALU reduce was ~5k
// cyc/wave; now: transposed f16 dump [64 c][128 n] + 16 MFMA/wave ~1k cyc).
// Rest identical to R10: ctx fused into GEMM1 (no ek/v HBM roundtrip),
// fused softmax(q), out = softq @ (ctx@W_out) via per-batch CW^T,
// GEMM 128x128/BK64/4-wave/64KB-LDS, 2 blocks/CU.

typedef _Float16 half4 __attribute__((ext_vector_type(4)));
typedef _Float16 half8 __attribute__((ext_vector_type(8)));
typedef float f32x4 __attribute__((ext_vector_type(4)));

// ---- workspace byte offsets ----
#define WS_XB 0UL             // x as f16           [16384][1024]   33.55MB
#define WS_WQKVT 33554432UL   // W_qkv^T f16        [1536][1024]     3.15MB
#define WS_CWT 37748736UL     // CW^T f16           [2][1024][512]   2.10MB
#define WS_CTXPART 54525952UL // ctx partials f32   [16][64][4096]  16.78MB
#define WS_COLPART 71303168UL // colsum partials f32[16][64][64]     0.26MB
#define WS_SQ 88080384UL      // softmax(q) f16     [16384][512]    16.78MB

__device__ __forceinline__ void gld16(const void* g, void* l) {
  // async global->LDS, 16B per lane; LDS dest = wave-uniform base + lane*16
  __builtin_amdgcn_global_load_lds(
      (const __attribute__((address_space(1))) unsigned int*)g,
      (__attribute__((address_space(3))) unsigned int*)l, 16, 0, 0);
}

// Fused prep: cvt x (f32->f16), transpose+cvt W_qkv.
__global__ void prep_kernel(const float* __restrict__ x,
                            const float* __restrict__ Wqkv,
                            _Float16* __restrict__ xb,
                            _Float16* __restrict__ wqkvT) {
  const int blk = blockIdx.x;
  if (blk < 16384) {
    int i = blk * 256 + threadIdx.x;  // 4 f32 per thread
    f32x4 v = *(const f32x4*)(x + (size_t)i * 4);
    half4 h = {(_Float16)v[0], (_Float16)v[1], (_Float16)v[2], (_Float16)v[3]};
    *(half4*)(xb + (size_t)i * 4) = h;
  } else {
    int i = (blk - 16384) * 256 + threadIdx.x;  // [0, 1536*1024)
    int c = i >> 10, r = i & 1023;
    wqkvT[i] = (_Float16)Wqkv[(size_t)r * 1536 + c];
  }
}

// ---------------- 128x128 BK=64 co-resident GEMM (R7-measured) -------------
// A[M][K] f16 row-major, BT[N][K] f16 row-major. 256 threads = 4 waves (2Mx2N),
// per-wave output 64x64 (acc[4][4]). LDS: 2 dbuf x (A 16KB + B 16KB) = 64KB.
// Tile layout [128 rows][128B], XOR swizzle byte ^= ((row&7)<<4); staged
// linearly via global_load_lds with inverse-swizzled global source column.

// stage one full 128x64-f16 tile region = 4 sweeps x 1 gld16/thread
__device__ __forceinline__ void stage_tile(const _Float16* __restrict__ G, int K,
                                           int rowbase, int kt, char* region,
                                           int t) {
  char* wbase = region + (t & ~63) * 16;  // + lane*16 done by HW
#pragma unroll
  for (int q = 0; q < 4; ++q) {
    const int row = q * 32 + (t >> 3);
    const int col8 = ((t & 7) ^ (row & 7)) * 8;  // inverse-swizzled f16 col
    gld16(G + (size_t)(rowbase + row) * K + kt + col8, wbase + q * 4096);
  }
}

// stage a 64-row tile region = 2 sweeps (for split kv B-tiles)
__device__ __forceinline__ void stage_tile64(const _Float16* __restrict__ G,
                                             int K, int rowbase, int kt,
                                             char* region, int t) {
  char* wbase = region + (t & ~63) * 16;
#pragma unroll
  for (int q = 0; q < 2; ++q) {
    const int row = q * 32 + (t >> 3);
    const int col8 = ((t & 7) ^ (row & 7)) * 8;
    gld16(G + (size_t)(rowbase + row) * K + kt + col8, wbase + q * 4096);
  }
}

// EPI 0: tileN<4 -> fused softmax(q) -> oQ[16384][512];
//        tileN>=4 -> head h=tileN-4, B-cols [k_h | v_h]; epilogue computes
//        64x64 partial ek^T v via MFMA + colsums -> ctxpart/colpart.
// EPI 1: +bias, f32 out ldc=1024 (A=softq, BT=CW^T per batch via bstride).
template <int EPI>
__global__ __launch_bounds__(256, 2) void gemm128(
    const _Float16* __restrict__ A, const _Float16* __restrict__ BT, int K,
    int NTN, int bstride, _Float16* __restrict__ oQ,
    float* __restrict__ ctxpart, float* __restrict__ colpart,
    float* __restrict__ oC, const float* __restrict__ bias) {
  __shared__ char lds[65536];
  const int t = threadIdx.x;
  const int l = t & 63, w = t >> 6;
  const int wm = w >> 1, wn = w & 1;  // wave -> 64x64 quadrant
  const int fr = l & 15, qq = l >> 4;
  const int swzx = (fr & 7) << 4;

  // T1: bijective XCD chunking (nwg % 8 == 0), tileM-major within chunk
  const int nwg = gridDim.x;
  const int cpx = nwg >> 3;
  const int wg = (blockIdx.x & 7) * cpx + (blockIdx.x >> 3);
  const int tileM = wg / NTN, tileN = wg - tileM * NTN;
  const int mbase = tileM * 128, nbase = tileN * 128;
  BT += (size_t)(tileM >> 6) * bstride;  // per-batch B (0 for GEMM1)

  const int NT = K >> 6;
  f32x4 acc[4][4] = {};
  half8 a[4][2], b[4][2];

  // stage both operands of K-tile `tile` into buffer (tile&1); 8 loads/thread
  auto STG = [&](int tile) {
    int kt = tile * 64;
    if (kt > K - 64) kt = K - 64;  // tail clamp: identical issue counts
    char* base = lds + ((tile & 1) << 15);
    stage_tile(A, K, mbase, kt, base, t);  // 4 loads
    if (EPI == 1 || tileN < 4) {
      stage_tile(BT, K, nbase, kt, base + 16384, t);  // 4 loads
    } else {
      const int h = tileN - 4;
      stage_tile64(BT, K, 512 + h * 64, kt, base + 16384, t);          // k_h
      stage_tile64(BT, K, 1024 + h * 64, kt, base + 16384 + 8192, t);  // v_h
    }
  };

  // prologue: tile0 + tile1 (16 loads/thread); vmcnt(8) -> tile0 resident
  STG(0);
  STG(1);
  asm volatile("s_waitcnt vmcnt(8)" ::: "memory");
  __builtin_amdgcn_s_barrier();

  for (int t2 = 0; t2 < NT; ++t2) {
    const char* ldsA = lds + ((t2 & 1) << 15);
    const char* ldsB = ldsA + 16384;
    // ph0: stage tile t2+1 -> other buffer (prev readers drained at ph1's
    // lgkmcnt(0) before BAR_b); then all frag reads from cur.
    STG(t2 + 1);
#pragma unroll
    for (int mi = 0; mi < 4; ++mi)
#pragma unroll
      for (int kk = 0; kk < 2; ++kk) {
        int off = (wm * 64 + mi * 16 + fr) * 128 + ((kk * 64 + qq * 16) ^ swzx);
        a[mi][kk] = *(const half8*)(ldsA + off);
      }
#pragma unroll
    for (int ni = 0; ni < 4; ++ni)
#pragma unroll
      for (int kk = 0; kk < 2; ++kk) {
        int off = (wn * 64 + ni * 16 + fr) * 128 + ((kk * 64 + qq * 16) ^ swzx);
        b[ni][kk] = *(const half8*)(ldsB + off);
      }
    __builtin_amdgcn_s_barrier();  // BAR_a
    __builtin_amdgcn_s_setprio(1);
#pragma unroll
    for (int mi = 0; mi < 4; ++mi)
#pragma unroll
      for (int ni = 0; ni < 2; ++ni)
#pragma unroll
        for (int kk = 0; kk < 2; ++kk)
          acc[mi][ni] = __builtin_amdgcn_mfma_f32_16x16x32_f16(
              a[mi][kk], b[ni][kk], acc[mi][ni], 0, 0, 0);
    __builtin_amdgcn_s_setprio(0);
    // ph1: drain this tile's ds_reads so next iter's STG->other is race-free;
    // drain stage loads (t2+1).
    asm volatile("s_waitcnt vmcnt(0) lgkmcnt(0)" ::: "memory");
    __builtin_amdgcn_s_barrier();  // BAR_b
    __builtin_amdgcn_s_setprio(1);
#pragma unroll
    for (int mi = 0; mi < 4; ++mi)
#pragma unroll
      for (int ni = 2; ni < 4; ++ni)
#pragma unroll
        for (int kk = 0; kk < 2; ++kk)
          acc[mi][ni] = __builtin_amdgcn_mfma_f32_16x16x32_f16(
              a[mi][kk], b[ni][kk], acc[mi][ni], 0, 0, 0);
    __builtin_amdgcn_s_setprio(0);
  }
  // no gld16/ds_read in flight here (drained at final ph1); LDS reusable.

  // C/D layout: col = lane&15 (=fr), row = (lane>>4)*4 + reg (=qq*4+r)
  if (EPI == 0) {
    if (tileN < 4) {
      // fused softmax over head dim (4 in-reg + shfl_xor<16), store softq
      const int gcol0 = nbase + wn * 64;
#pragma unroll
      for (int mi = 0; mi < 4; ++mi) {
        const int grow = mbase + wm * 64 + mi * 16 + qq * 4;
        float e[4][4], rs[4];
#pragma unroll
        for (int r = 0; r < 4; ++r) {
          float s = 0.f;
#pragma unroll
          for (int ni = 0; ni < 4; ++ni) {
            e[ni][r] = __expf(acc[mi][ni][r]);
            s += e[ni][r];
          }
#pragma unroll
          for (int off = 1; off < 16; off <<= 1) s += __shfl_xor(s, off, 64);
          rs[r] = 1.f / s;
        }
#pragma unroll
        for (int ni = 0; ni < 4; ++ni) {
          const int gcol = gcol0 + ni * 16 + fr;
#pragma unroll
          for (int r = 0; r < 4; ++r)
            oQ[(size_t)(grow + r) * 512 + gcol] = (_Float16)(e[ni][r] * rs[r]);
        }
      }
    } else {
      // kv path (MFMA ctx): local cols 0-63 = k logits (wn=0), 64-127 = v.
      const int h = tileN - 4;
      float* credu = (float*)(lds + 32768);  // [2][64] colsum partials
      // exp on k-quadrant + in-register colsum (sum over this wave's 64 n)
      if (wn == 0) {
#pragma unroll
        for (int mi = 0; mi < 4; ++mi)
#pragma unroll
          for (int ni = 0; ni < 4; ++ni) {
            f32x4 e4;
#pragma unroll
            for (int r = 0; r < 4; ++r) e4[r] = __expf(acc[mi][ni][r]);
            acc[mi][ni] = e4;
          }
        float s[4] = {};
#pragma unroll
        for (int ni = 0; ni < 4; ++ni) {
#pragma unroll
          for (int mi = 0; mi < 4; ++mi)
#pragma unroll
            for (int r = 0; r < 4; ++r) s[ni] += acc[mi][ni][r];
          s[ni] += __shfl_xor(s[ni], 16, 64);
          s[ni] += __shfl_xor(s[ni], 32, 64);
        }
        if (l < 16) {
#pragma unroll
          for (int ni = 0; ni < 4; ++ni) credu[wm * 64 + ni * 16 + fr] = s[ni];
        }
      }
      // transposed f16 dump: ekT[64 c][128 n] @lds+0, vT @lds+16384;
      // swizzle: byte ^= ((c&15)<<4) on the n-offset (16B-chunk involution)
      {
        char* dst8 = lds + (wn ? 16384 : 0);
#pragma unroll
        for (int mi = 0; mi < 4; ++mi) {
          const int nb = (wm * 64 + mi * 16 + qq * 4) * 2;  // n byte offset
#pragma unroll
          for (int ni = 0; ni < 4; ++ni) {
            const int c = ni * 16 + fr;
            half4 pk = {(_Float16)acc[mi][ni][0], (_Float16)acc[mi][ni][1],
                        (_Float16)acc[mi][ni][2], (_Float16)acc[mi][ni][3]};
            *(half4*)(dst8 + c * 256 + (nb ^ ((c & 15) << 4))) = pk;
          }
        }
      }
      __syncthreads();
      // MFMA: D[d][e] = sum_n ekT[d][n]*vT[e][n]; wave w -> e in [w*16,+16)
      half8 bf[4];
      const int erow = w * 16 + fr;
#pragma unroll
      for (int kk = 0; kk < 4; ++kk)
        bf[kk] = *(const half8*)(lds + 16384 + erow * 256 +
                                 ((kk * 64 + qq * 16) ^ ((erow & 15) << 4)));
      f32x4 dacc[4] = {};
#pragma unroll
      for (int mi = 0; mi < 4; ++mi) {
        const int drow = mi * 16 + fr;
#pragma unroll
        for (int kk = 0; kk < 4; ++kk) {
          half8 af = *(const half8*)(lds + drow * 256 +
                                     ((kk * 64 + qq * 16) ^ ((drow & 15) << 4)));
          dacc[mi] =
              __builtin_amdgcn_mfma_f32_16x16x32_f16(af, bf[kk], dacc[mi], 0, 0, 0);
        }
      }
      const int bh = (tileM >> 6) * 8 + h, chunk = tileM & 63;
      float* cp = ctxpart + ((size_t)bh * 64 + chunk) * 4096;
#pragma unroll
      for (int mi = 0; mi < 4; ++mi)
#pragma unroll
        for (int r = 0; r < 4; ++r)
          cp[(mi * 16 + qq * 4 + r) * 64 + w * 16 + fr] = dacc[mi][r];
      if (t < 16) {
        f32x4 c0 = *(const f32x4*)&credu[t * 4];
        f32x4 c1 = *(const f32x4*)&credu[64 + t * 4];
        *(f32x4*)&colpart[((size_t)bh * 64 + chunk) * 64 + t * 4] = c0 + c1;
      }
    }
  } else {
#pragma unroll
    for (int mi = 0; mi < 4; ++mi) {
      const int grow = mbase + wm * 64 + mi * 16 + qq * 4;
#pragma unroll
      for (int ni = 0; ni < 4; ++ni) {
        const int gcol = nbase + wn * 64 + ni * 16 + fr;
        const float bb = bias[gcol];
#pragma unroll
        for (int r = 0; r < 4; ++r)
          oC[(size_t)(grow + r) * 1024 + gcol] = acc[mi][ni][r] + bb;
      }
    }
  }
}

// Merged reduce + CW^T: block = (bh, d). Reduces 64 chunk-partials, divides
// by colsum, then CW^T[b][o][h*64+d] = sum_e crow[e]*Wout[h*64+e][o].
__global__ __launch_bounds__(256) void ctxw_kernel(
    const float* __restrict__ ctxpart, const float* __restrict__ colpart,
    const float* __restrict__ Wout, _Float16* __restrict__ cwT) {
  __shared__ float part[4][64];
  __shared__ float csp[64];
  __shared__ float crow[64];
  const int blk = blockIdx.x;
  const int bh = blk >> 6, d = blk & 63;
  const int b = bh >> 3, h = bh & 7;
  const int t = threadIdx.x;
  const int e = t & 63, cq = t >> 6;
  float p = 0.f;
#pragma unroll
  for (int cc = 0; cc < 16; ++cc)
    p += ctxpart[((size_t)bh * 64 + cq * 16 + cc) * 4096 + d * 64 + e];
  part[cq][e] = p;
  if (t >= 64 && t < 128)
    csp[t - 64] = colpart[((size_t)bh * 64 + (t - 64)) * 64 + d];
  __syncthreads();
  if (t < 64) {
    float csum = 0.f;
#pragma unroll
    for (int c = 0; c < 64; ++c) csum += csp[c];
    crow[t] = (part[0][t] + part[1][t] + part[2][t] + part[3][t]) / csum;
  }
  __syncthreads();
  float acc[4] = {};
  for (int e2 = 0; e2 < 64; ++e2) {
    const float c = crow[e2];
    const float* wr = Wout + (size_t)(h * 64 + e2) * 1024 + t;
#pragma unroll
    for (int j = 0; j < 4; ++j) acc[j] += c * wr[j * 256];
  }
  _Float16* dst = cwT + (size_t)b * 524288 + (size_t)t * 512 + h * 64 + d;
#pragma unroll
  for (int j = 0; j < 4; ++j) dst[(size_t)j * 256 * 512] = (_Float16)acc[j];
}

extern "C" void kernel_launch(void* const* d_in, const int* in_sizes, int n_in,
                              void* d_out, int out_size, void* d_ws, size_t ws_size,
                              hipStream_t stream) {
  const float* x = (const float*)d_in[0];
  const float* Wqkv = (const float*)d_in[1];
  const float* Wout = (const float*)d_in[2];
  const float* bout = (const float*)d_in[3];
  float* out = (float*)d_out;
  char* ws = (char*)d_ws;

  _Float16* xb = (_Float16*)(ws + WS_XB);
  _Float16* wqkvT = (_Float16*)(ws + WS_WQKVT);
  _Float16* cwT = (_Float16*)(ws + WS_CWT);
  _Float16* sq = (_Float16*)(ws + WS_SQ);
  float* ctxpart = (float*)(ws + WS_CTXPART);
  float* colpart = (float*)(ws + WS_COLPART);

  // 1) fused converts (x cvt + W_qkv transpose)
  prep_kernel<<<22528, 256, 0, stream>>>(x, Wqkv, xb, wqkvT);
  // 2) qkv projection; q blocks -> fused softmax -> sq; kv blocks -> fused
  //    MFMA partial-context -> ctxpart/colpart
  gemm128<0><<<1536, 256, 0, stream>>>(xb, wqkvT, 1024, 12, 0, sq, ctxpart,
                                       colpart, nullptr, nullptr);
  // 3) reduce + CW^T = (ctx @ W_out)^T per batch
  ctxw_kernel<<<1024, 256, 0, stream>>>(ctxpart, colpart, Wout, cwT);
  // 4) out = softq @ CW + b  (M=16384,N=1024,K=512; B selected per batch)
  gemm128<1><<<1024, 256, 0, stream>>>(sq, cwT, 512, 8, 524288, nullptr,
                                       nullptr, nullptr, out, bout);
}